// Round 5
// baseline (163.651 us; speedup 1.0000x reference)
//
#include <hip/hip_runtime.h>

#define NN   32768
#define HD   128
#define EE   524288
#define GG   256
#define EPG  2048
#define CCd  16
#define LLd  3

typedef short short8 __attribute__((ext_vector_type(8)));   // 8 bf16 = 4 VGPRs
typedef float f32x4 __attribute__((ext_vector_type(4)));

__device__ __forceinline__ unsigned short f2bf(float f) {
  unsigned u = __builtin_bit_cast(unsigned, f);
  return (unsigned short)((u + 0x7FFFu + ((u >> 16) & 1u)) >> 16);  // RNE
}
__device__ __forceinline__ unsigned bfpack(float a, float b) {
  return (unsigned)f2bf(a) | ((unsigned)f2bf(b) << 16);
}

// ---------------- convert weights to bf16 + reg_loss accumulate (verified R4) ----------------
__global__ __launch_bounds__(256) void convert_w_kernel(const float* __restrict__ Wn, const float* __restrict__ Wo,
                                                        const float* __restrict__ Wr, const float* __restrict__ bo,
                                                        unsigned* __restrict__ Wnb, unsigned* __restrict__ Wob,
                                                        unsigned* __restrict__ Wrb, float* __restrict__ wsreg) {
  int i = blockIdx.x * 256 + threadIdx.x;
  float4 a = *(const float4*)(Wn + (size_t)i * 4);
  float4 b = *(const float4*)(Wo + (size_t)i * 4);
  float4 c = *(const float4*)(Wr + (size_t)i * 4);
  *(uint2*)(Wnb + (size_t)i * 2) = make_uint2(bfpack(a.x, a.y), bfpack(a.z, a.w));
  *(uint2*)(Wob + (size_t)i * 2) = make_uint2(bfpack(b.x, b.y), bfpack(b.z, b.w));
  *(uint2*)(Wrb + (size_t)i * 2) = make_uint2(bfpack(c.x, c.y), bfpack(c.z, c.w));
  float s = fabsf(b.x) + fabsf(b.y) + fabsf(b.z) + fabsf(b.w);
  if (blockIdx.x == 0 && threadIdx.x < 96) {
    float4 d = *(const float4*)(bo + threadIdx.x * 4);
    s += fabsf(d.x) + fabsf(d.y) + fabsf(d.z) + fabsf(d.w);
  }
#pragma unroll
  for (int mk = 1; mk < 64; mk <<= 1) s += __shfl_xor(s, mk, 64);
  if ((threadIdx.x & 63) == 0) atomicAdd(wsreg, s);
}

// ---------------- per-graph dense adjacency (scaled bf16) + fin/fout (verified R4) ----------------
__global__ __launch_bounds__(256) void build_m_kernel(const int* __restrict__ src, const int* __restrict__ tgt,
                                                      const int* __restrict__ mask,
                                                      unsigned* __restrict__ Mb, float* __restrict__ fin,
                                                      float* __restrict__ fout) {
  __shared__ unsigned Mi[2 * 128 * 64];   // 64 KB packed u16 counts [dir][t][s/2]
  const int g = blockIdx.x;
  const int tid = threadIdx.x;
  for (int i = tid; i < 16384; i += 256) Mi[i] = 0;
  __syncthreads();
  const int e0 = g * EPG;
#pragma unroll
  for (int i = 0; i < 8; ++i) {
    int e = e0 + i * 256 + tid;
    int t = tgt[e] & 127;
    int sl = src[e] & 127;
    int dir = (mask[e] != 0) ? 0 : 1;
    atomicAdd(&Mi[dir * 8192 + t * 64 + (sl >> 1)], 1u << ((sl & 1) * 16));
  }
  __syncthreads();
  const int t = tid >> 1, p = tid & 1;
  unsigned nin = 0, nout = 0;
#pragma unroll 4
  for (int k = 0; k < 32; ++k) { unsigned v = Mi[t * 64 + p * 32 + k]; nin += (v & 0xffffu) + (v >> 16); }
#pragma unroll 4
  for (int k = 0; k < 32; ++k) { unsigned v = Mi[8192 + t * 64 + p * 32 + k]; nout += (v & 0xffffu) + (v >> 16); }
  nin += __shfl_xor((int)nin, 1);
  nout += __shfl_xor((int)nout, 1);
  unsigned dg = nin + nout;
  float inv = 1.0f / (float)(dg > 0 ? dg : 1);
  if (p == 0) { fin[g * 128 + t] = (float)nin * inv; fout[g * 128 + t] = (float)nout * inv; }
#pragma unroll
  for (int dir = 0; dir < 2; ++dir) {
    int base = dir * 8192 + t * 64 + p * 32;
#pragma unroll
    for (int k4 = 0; k4 < 8; ++k4) {
      uint4 v = *(const uint4*)&Mi[base + k4 * 4];
      uint4 o;
      o.x = bfpack((float)(v.x & 0xffffu) * inv, (float)(v.x >> 16) * inv);
      o.y = bfpack((float)(v.y & 0xffffu) * inv, (float)(v.y >> 16) * inv);
      o.z = bfpack((float)(v.z & 0xffffu) * inv, (float)(v.z >> 16) * inv);
      o.w = bfpack((float)(v.w & 0xffffu) * inv, (float)(v.w >> 16) * inv);
      *(uint4*)&Mb[(size_t)g * 16384 + base + k4 * 4] = o;
    }
  }
}

// ---------------- fully fused per-graph network, v2 ----------------
// grid 256 (1 block/graph), 512 threads (8 waves). h kept row-major [t][f] in LDS.
// Per layer: pre = h*Wr^T  +  sum_sc [ M~in[:,sc]*(h[sc]*Wn^T) + M~out[:,sc]*(h[sc]*Wo^T) ]
// W and M~ fragments come straight from global (L2-resident, contiguous 16B per lane).
// Ysc buffer holds the per-chunk Y/Z in [c][s] order so consume B-frags are b128 row reads.
#define SSTR 136   // scratch stride in shorts (128 data + 8 pad -> 4-bank row step)
#define YSTR 40    // ysc stride in shorts (32 data + 8 pad)
__global__ __launch_bounds__(512) void fused_kernel(
    const float* __restrict__ x, const unsigned short* __restrict__ Mb,
    const unsigned short* __restrict__ Wnb, const unsigned short* __restrict__ Wob,
    const unsigned short* __restrict__ Wrb,
    const float* __restrict__ bn, const float* __restrict__ bo,
    const float* __restrict__ fin, const float* __restrict__ fout,
    const float* __restrict__ lng, const float* __restrict__ lnb,
    const float* __restrict__ s,
    const float* __restrict__ flng, const float* __restrict__ flnb,
    const float* __restrict__ linw, const float* __restrict__ bias,
    float* __restrict__ out, float* __restrict__ l1g) {
  __shared__ unsigned short scratch[128 * SSTR];  // 34.0 KB  h [t][f] bf16
  __shared__ unsigned short ys[2 * 128 * YSTR];   // 20.0 KB  Y/Z chunk [op][c][s_local]
  __shared__ unsigned short sTs[16 * SSTR];       //  4.3 KB  s^T [c][t] bf16
  __shared__ float colsumS[CCd];
  __shared__ float xcs[CCd], axcs[CCd], msk[CCd];

  const int g = blockIdx.x;
  const int tid = threadIdx.x;
  const int wave = tid >> 6;
  const int lane = tid & 63;
  const int m = lane & 15;
  const int q = lane >> 4;
  const unsigned short* Mg = Mb + (size_t)g * 32768;       // [op][t][s]
  unsigned* scratch32 = (unsigned*)scratch;

  // ---- init: x -> scratch [t][f] bf16 (coalesced loads, paired b32 LDS writes) ----
  {
    const float4* xg = (const float4*)(x + (size_t)g * 16384);
#pragma unroll
    for (int i = 0; i < 8; ++i) {
      int flat = i * 512 + tid;              // 4096 float4s
      int t = flat >> 5, f = (flat & 31) << 2;
      float4 v = xg[flat];
      int w0 = (t * SSTR + f) >> 1;
      scratch32[w0] = bfpack(v.x, v.y);
      scratch32[w0 + 1] = bfpack(v.z, v.w);
    }
    int t = tid >> 2, c0 = (tid & 3) << 2;
    float4 v = *(const float4*)(s + (size_t)g * 2048 + t * 16 + c0);
    sTs[(c0 + 0) * SSTR + t] = f2bf(v.x);
    sTs[(c0 + 1) * SSTR + t] = f2bf(v.y);
    sTs[(c0 + 2) * SSTR + t] = f2bf(v.z);
    sTs[(c0 + 3) * SSTR + t] = f2bf(v.w);
    if (tid < CCd) {
      float cs = 0.f;
      for (int tt = 0; tt < 128; ++tt) cs += s[(size_t)g * 2048 + tt * 16 + tid];
      colsumS[tid] = cs;
    }
  }
  __syncthreads();

  for (int L = 0; L < LLd; ++L) {
    const unsigned short* WnL = Wnb + (size_t)L * 16384;
    const unsigned short* WoL = Wob + (size_t)L * 16384;
    const unsigned short* WrL = Wrb + (size_t)L * 16384;
    f32x4 pre[8];
#pragma unroll
    for (int ct = 0; ct < 8; ++ct) pre[ct] = (f32x4){0.f, 0.f, 0.f, 0.f};

    // --- R-phase: pre += h * Wr^T  (A = own t-rows from scratch, B = Wr global) ---
#pragma unroll
    for (int ks = 0; ks < 4; ++ks) {
      short8 a = *(const short8*)&scratch[(wave * 16 + m) * SSTR + ks * 32 + q * 8];
#pragma unroll
      for (int ct = 0; ct < 8; ++ct) {
        short8 b = *(const short8*)(WrL + (size_t)(ct * 16 + m) * 128 + ks * 32 + q * 8);
        pre[ct] = __builtin_amdgcn_mfma_f32_16x16x32_bf16(a, b, pre[ct], 0, 0, 0);
      }
    }

    // cache this wave's Wn/Wo B-frags (column slice c = 16*wave + m) for all 4 k-chunks
    short8 wnf[4], wof[4];
#pragma unroll
    for (int ks = 0; ks < 4; ++ks) {
      wnf[ks] = *(const short8*)(WnL + (size_t)(wave * 16 + m) * 128 + ks * 32 + q * 8);
      wof[ks] = *(const short8*)(WoL + (size_t)(wave * 16 + m) * 128 + ks * 32 + q * 8);
    }

    // --- s-chunk loop: Y/Z = h[chunk]*W^T -> ysc; pre += M~[:,chunk]*Ysc ---
    for (int sc = 0; sc < 4; ++sc) {
      f32x4 ya[2][2];  // [op][stile]
#pragma unroll
      for (int o2 = 0; o2 < 2; ++o2)
#pragma unroll
        for (int st = 0; st < 2; ++st) ya[o2][st] = (f32x4){0.f, 0.f, 0.f, 0.f};
#pragma unroll
      for (int ks = 0; ks < 4; ++ks) {
        short8 a0 = *(const short8*)&scratch[(sc * 32 + m) * SSTR + ks * 32 + q * 8];
        short8 a1 = *(const short8*)&scratch[(sc * 32 + 16 + m) * SSTR + ks * 32 + q * 8];
        ya[0][0] = __builtin_amdgcn_mfma_f32_16x16x32_bf16(a0, wnf[ks], ya[0][0], 0, 0, 0);
        ya[0][1] = __builtin_amdgcn_mfma_f32_16x16x32_bf16(a1, wnf[ks], ya[0][1], 0, 0, 0);
        ya[1][0] = __builtin_amdgcn_mfma_f32_16x16x32_bf16(a0, wof[ks], ya[1][0], 0, 0, 0);
        ya[1][1] = __builtin_amdgcn_mfma_f32_16x16x32_bf16(a1, wof[ks], ya[1][1], 0, 0, 0);
      }
      // write Y/Z chunk as [op][c = 16w+m][s_local = st*16 + 4q + r]
#pragma unroll
      for (int o2 = 0; o2 < 2; ++o2)
#pragma unroll
        for (int st = 0; st < 2; ++st)
#pragma unroll
          for (int r = 0; r < 4; ++r)
            ys[o2 * 128 * YSTR + (wave * 16 + m) * YSTR + st * 16 + q * 4 + r] = f2bf(ya[o2][st][r]);
      __syncthreads();
      // consume: pre += M~op[t-rows, s-chunk] * Ychunk
#pragma unroll
      for (int o2 = 0; o2 < 2; ++o2) {
        short8 am = *(const short8*)(Mg + (size_t)o2 * 16384 + (size_t)(wave * 16 + m) * 128 + sc * 32 + q * 8);
#pragma unroll
        for (int ct = 0; ct < 8; ++ct) {
          short8 b = *(const short8*)&ys[o2 * 128 * YSTR + (ct * 16 + m) * YSTR + q * 8];
          pre[ct] = __builtin_amdgcn_mfma_f32_16x16x32_bf16(am, b, pre[ct], 0, 0, 0);
        }
      }
      if (sc < 3) __syncthreads();
    }

    // --- epilogue: bias mix + LN + ReLU -> scratch rows [16w .. 16w+16) ---
    float bnv[8], bov[8], gv[8], bv[8];
#pragma unroll
    for (int ct = 0; ct < 8; ++ct) {
      int c = L * 128 + ct * 16 + m;
      bnv[ct] = bn[c]; bov[ct] = bo[c]; gv[ct] = lng[c]; bv[ct] = lnb[c];
    }
#pragma unroll
    for (int r = 0; r < 4; ++r) {
      const int tl = q * 4 + r;
      const int T = g * 128 + wave * 16 + tl;
      const float fiv = fin[T], fov = fout[T];
      float v[8];
      float sum = 0.f;
#pragma unroll
      for (int ct = 0; ct < 8; ++ct) {
        v[ct] = pre[ct][r] + fiv * bnv[ct] + fov * bov[ct];
        sum += v[ct];
      }
      sum += __shfl_xor(sum, 1); sum += __shfl_xor(sum, 2);
      sum += __shfl_xor(sum, 4); sum += __shfl_xor(sum, 8);
      const float mu = sum * (1.0f / 128.0f);
      float sq = 0.f;
#pragma unroll
      for (int ct = 0; ct < 8; ++ct) { float d = v[ct] - mu; sq += d * d; }
      sq += __shfl_xor(sq, 1); sq += __shfl_xor(sq, 2);
      sq += __shfl_xor(sq, 4); sq += __shfl_xor(sq, 8);
      const float rstd = rsqrtf(sq * (1.0f / 128.0f) + 1e-5f);
#pragma unroll
      for (int ct = 0; ct < 8; ++ct) {
        float o = fmaxf((v[ct] - mu) * rstd * gv[ct] + bv[ct], 0.0f);
        scratch[(wave * 16 + tl) * SSTR + ct * 16 + m] = f2bf(o);
      }
    }
    __syncthreads();
  }

  // ---- pool: pooled[c][fo] = sum_t s[t][c]*h[t][fo]; wave w owns fo-tile w ----
  f32x4 pl = (f32x4){0.f, 0.f, 0.f, 0.f};
#pragma unroll
  for (int ks = 0; ks < 4; ++ks) {
    short8 a = *(const short8*)&sTs[m * SSTR + ks * 32 + q * 8];
    short8 b;
#pragma unroll
    for (int j = 0; j < 8; ++j)
      b[j] = (short)scratch[(ks * 32 + q * 8 + j) * SSTR + wave * 16 + m];
    pl = __builtin_amdgcn_mfma_f32_16x16x32_bf16(a, b, pl, 0, 0, 0);
  }
  float* pooledS = (float*)ys;   // reuse ysc region: 16 x 132 fp32
#pragma unroll
  for (int r = 0; r < 4; ++r) pooledS[(q * 4 + r) * 132 + wave * 16 + m] = pl[r];
  __syncthreads();

  // ---- final LN + lin + mask (threads 0..255; verified R4) ----
  if (tid < 256) {
    const int c = tid >> 4;
    const int j0 = (tid & 15) << 3;
    float v[8];
#pragma unroll
    for (int jj = 0; jj < 8; ++jj) v[jj] = pooledS[c * 132 + j0 + jj];
    float sum = 0.f;
#pragma unroll
    for (int jj = 0; jj < 8; ++jj) sum += v[jj];
#pragma unroll
    for (int mk = 1; mk < 16; mk <<= 1) sum += __shfl_xor(sum, mk, 64);
    float mu = sum * (1.0f / 128.0f);
    float sq = 0.f;
#pragma unroll
    for (int jj = 0; jj < 8; ++jj) { float d = v[jj] - mu; sq += d * d; }
#pragma unroll
    for (int mk = 1; mk < 16; mk <<= 1) sq += __shfl_xor(sq, mk, 64);
    float rstd = rsqrtf(sq * (1.0f / 128.0f) + 1e-5f);
    float dot = 0.f;
#pragma unroll
    for (int jj = 0; jj < 8; ++jj) {
      float nv = (v[jj] - mu) * rstd * flng[j0 + jj] + flnb[j0 + jj];
      dot += nv * linw[j0 + jj];
    }
#pragma unroll
    for (int mk = 1; mk < 16; mk <<= 1) dot += __shfl_xor(dot, mk, 64);
    if ((tid & 15) == 0) {
      float cm = (colsumS[c] > 0.f) ? 1.0f : 0.0f;
      float xcv = dot * cm;
      out[257 + g * CCd + c] = xcv;
      xcs[c] = xcv; axcs[c] = fabsf(xcv); msk[c] = cm;
    }
  }
  __syncthreads();
  if (tid == 0) {
    float so = 0.f, sa = 0.f, sd = 0.f;
#pragma unroll
    for (int k = 0; k < CCd; ++k) { so += xcs[k]; sa += axcs[k]; sd += msk[k] + 1e-7f; }
    out[g] = so + bias[0];
    l1g[g] = sa / sd;
  }
}

// ---------------- combine: losses = 0.01*reg + 0.01*mean_g(l1g) ----------------
__global__ __launch_bounds__(256) void combine_kernel(const float* __restrict__ l1g, const float* __restrict__ wsreg,
                                                      float* __restrict__ outp) {
  const int tid = threadIdx.x;
  float s2 = l1g[tid];
#pragma unroll
  for (int mk = 1; mk < 64; mk <<= 1) s2 += __shfl_xor(s2, mk, 64);
  __shared__ float rs2[4];
  if ((tid & 63) == 0) rs2[tid >> 6] = s2;
  __syncthreads();
  if (tid == 0) {
    float l1 = (rs2[0] + rs2[1] + rs2[2] + rs2[3]) * (1.0f / GG);
    outp[0] = 0.01f * wsreg[0] + 0.01f * l1;
  }
}

extern "C" void kernel_launch(void* const* d_in, const int* in_sizes, int n_in,
                              void* d_out, int out_size, void* d_ws, size_t ws_size,
                              hipStream_t stream) {
  (void)in_sizes; (void)n_in; (void)out_size; (void)ws_size;
  const float* x    = (const float*)d_in[0];
  const int*   ei   = (const int*)d_in[1];
  const int*   mask = (const int*)d_in[2];
  const float* s    = (const float*)d_in[3];
  const float* Wn   = (const float*)d_in[5];
  const float* bn   = (const float*)d_in[6];
  const float* Wo   = (const float*)d_in[7];
  const float* bo   = (const float*)d_in[8];
  const float* Wr   = (const float*)d_in[9];
  const float* lng  = (const float*)d_in[10];
  const float* lnb  = (const float*)d_in[11];
  const float* flng = (const float*)d_in[12];
  const float* flnb = (const float*)d_in[13];
  const float* linw = (const float*)d_in[14];
  const float* bias = (const float*)d_in[15];
  float* out = (float*)d_out;

  char* ws = (char*)d_ws;
  size_t off = 0;
  auto alloc = [&](size_t b) { char* p = ws + off; off += (b + 255) & ~(size_t)255; return p; };
  unsigned short* Mbuf = (unsigned short*)alloc((size_t)GG * 2 * 128 * 128 * 2);  // 16.8 MB
  float* fin    = (float*)alloc((size_t)NN * 4);
  float* fout   = (float*)alloc((size_t)NN * 4);
  unsigned short* Wnb = (unsigned short*)alloc((size_t)LLd * HD * HD * 2);
  unsigned short* Wob = (unsigned short*)alloc((size_t)LLd * HD * HD * 2);
  unsigned short* Wrb = (unsigned short*)alloc((size_t)LLd * HD * HD * 2);
  float* l1g    = (float*)alloc((size_t)GG * 4);
  float* wsreg  = (float*)alloc(256);

  const int* srcA = ei;
  const int* tgtA = ei + EE;

  hipMemsetAsync(wsreg, 0, 4, stream);
  convert_w_kernel<<<LLd * HD * HD / (256 * 4), 256, 0, stream>>>(Wn, Wo, Wr, bo,
      (unsigned*)Wnb, (unsigned*)Wob, (unsigned*)Wrb, wsreg);
  build_m_kernel<<<GG, 256, 0, stream>>>(srcA, tgtA, mask, (unsigned*)Mbuf, fin, fout);
  fused_kernel<<<GG, 512, 0, stream>>>(x, Mbuf, Wnb, Wob, Wrb, bn, bo, fin, fout,
                                       lng, lnb, s, flng, flnb, linw, bias, out, l1g);
  combine_kernel<<<1, 256, 0, stream>>>(l1g, wsreg, out + 256);
}